// Round 6
// baseline (306.593 us; speedup 1.0000x reference)
//
#include <hip/hip_runtime.h>
#include <hip/hip_bf16.h>

#define B_TOT   16384
#define D_IN    784
#define H_DIM   100
#define C_DIM   10
#define HP      128
#define KP      832      // 13 * 64, padded K
#define NDR     13
#define WG_ROWS 16
#define NGR     196      // 16B granules per source row (784*4/16)
#define NG      (WG_ROWS * NGR)   // 3136 granules per (tt) tile
#define PITCHB  1680     // LDS row pitch bytes (105 x 16B granules)

typedef __bf16 bf16x8 __attribute__((ext_vector_type(8)));
typedef float  f32x4  __attribute__((ext_vector_type(4)));
typedef unsigned short u16x4 __attribute__((ext_vector_type(4)));
typedef unsigned int   u32x4 __attribute__((ext_vector_type(4)));

static __device__ __forceinline__ unsigned short f32_to_bf16(float f) {
    unsigned int u = __float_as_uint(f);
    unsigned int r = (u + 0x7FFFu + ((u >> 16) & 1u)) >> 16;
    return (unsigned short)r;
}

__global__ void prep_kernel(const float* __restrict__ W1, const float* __restrict__ b1,
                            unsigned short* __restrict__ w1hi, unsigned short* __restrict__ w1lo,
                            float* __restrict__ b1p) {
    int idx = blockIdx.x * 256 + threadIdx.x;
    if (idx < HP) b1p[idx] = (idx < H_DIM) ? b1[idx] : 0.0f;
    if (idx < HP * KP) {
        int h = idx / KP, k = idx - h * KP;
        float v = (h < H_DIM && k < D_IN) ? W1[h * D_IN + k] : 0.0f;
        unsigned short hi = f32_to_bf16(v);
        float fh = __uint_as_float(((unsigned int)hi) << 16);
        unsigned short lo = f32_to_bf16(v - fh);
        w1hi[idx] = hi;
        w1lo[idx] = lo;
    }
}

// Full-K streaming staging; 2 barriers per pass; 2 WG/CU.
__global__ __launch_bounds__(256, 2)
void snn_main(const float* __restrict__ inp, const float* __restrict__ rnd,
              const unsigned short* __restrict__ w1hi, const unsigned short* __restrict__ w1lo,
              const float* __restrict__ b1p, const float* __restrict__ W2,
              const float* __restrict__ b2, float* __restrict__ out)
{
    // [2 tt][16 rows][105 x 16B granules, XOR-swizzled]: 53,760 B
    __shared__ __align__(16) unsigned short s_spike[2 * WG_ROWS * (PITCHB / 2)];
    __shared__ float s_cnt[WG_ROWS][HP];   // 8 KB

    const int tid  = threadIdx.x;
    const int lane = tid & 63;
    const int wid  = tid >> 6;
    const int n_off = wid * 32;          // each wave owns 32 of 128 H-cols
    const int row0 = blockIdx.x * WG_ROWS;

    const int l15 = lane & 15;
    const int l4  = lane >> 4;
    const size_t BD = (size_t)B_TOT * D_IN;

    // zero-init entire spike buffer once (pad cols >= 784 stay zero forever)
    for (int g = tid; g < 2 * WG_ROWS * 105; g += 256)
        *reinterpret_cast<u32x4*>(reinterpret_cast<char*>(s_spike) + g * 16) = (u32x4)0;

    float b1v[2];
#pragma unroll
    for (int nt = 0; nt < 2; ++nt) b1v[nt] = b1p[n_off + nt * 16 + l15];

    f32x4 mem1[2], cnt[2];
#pragma unroll
    for (int nt = 0; nt < 2; ++nt) { mem1[nt] = (f32x4)0.0f; cnt[nt] = (f32x4)0.0f; }

    for (int tp = 0; tp < 4; ++tp) {     // 4 passes x 2 timesteps
        __syncthreads();                 // prev pass MFMA reads done / init visible

        // ---- stage: full-K, flat granule sweep (stream-contiguous per wave instr) ----
#pragma unroll
        for (int tt = 0; tt < 2; ++tt) {
            const size_t tb = (size_t)(tp * 2 + tt) * BD;
#pragma unroll 4
            for (int i = 0; i < 13; ++i) {
                const int rc  = tid + i * 256;
                const int rcc = rc < NG ? rc : NG - 1;   // clamp (loads unconditional)
                const int r   = rcc / NGR;
                const int c   = rcc - r * NGR;
                const float* gr = rnd + tb + (size_t)(row0 + r) * D_IN + c * 4;
                const float* gi = inp + (size_t)(row0 + r) * D_IN + c * 4;
                f32x4 rv = __builtin_nontemporal_load(reinterpret_cast<const f32x4*>(gr));
                f32x4 iv = *reinterpret_cast<const f32x4*>(gi);
                u16x4 s;
#pragma unroll
                for (int j = 0; j < 4; ++j) {
                    unsigned short sg = iv[j] > 0.0f ? (unsigned short)0x3F80
                                      : (iv[j] < 0.0f ? (unsigned short)0xBF80 : (unsigned short)0);
                    s[j] = (rv[j] * 2.0f <= fabsf(iv[j])) ? sg : (unsigned short)0;
                }
                if (rc < NG) {
                    const int b16 = (c >> 1) ^ (r & 7);   // XOR-swizzled 16B granule
                    char* dst = reinterpret_cast<char*>(s_spike) +
                                (tt * WG_ROWS + r) * PITCHB + b16 * 16 + (c & 1) * 8;
                    *reinterpret_cast<u16x4*>(dst) = s;
                }
            }
        }
        __syncthreads();                 // spikes visible

        // ---- compute: full-K MFMA sweep, no barriers inside ----
        f32x4 acc[2][2];                 // [tt][nt]
#pragma unroll
        for (int a_ = 0; a_ < 2; ++a_)
#pragma unroll
            for (int b_ = 0; b_ < 2; ++b_) acc[a_][b_] = (f32x4)0.0f;

        for (int dr = 0; dr < NDR; ++dr) {
#pragma unroll
            for (int cc = 0; cc < 2; ++cc) {
                bf16x8 bh[2], blo[2];
#pragma unroll
                for (int nt = 0; nt < 2; ++nt) {
                    int off = (n_off + nt * 16 + l15) * KP + dr * 64 + cc * 32 + l4 * 8;
                    bh[nt]  = *reinterpret_cast<const bf16x8*>(w1hi + off);
                    blo[nt] = *reinterpret_cast<const bf16x8*>(w1lo + off);
                }
#pragma unroll
                for (int tt = 0; tt < 2; ++tt) {
                    const int g16 = (dr * 8 + cc * 4 + l4) ^ (l15 & 7);
                    const char* asrc = reinterpret_cast<const char*>(s_spike) +
                                       (tt * WG_ROWS + l15) * PITCHB + g16 * 16;
                    bf16x8 a = *reinterpret_cast<const bf16x8*>(asrc);
#pragma unroll
                    for (int nt = 0; nt < 2; ++nt) {
                        acc[tt][nt] = __builtin_amdgcn_mfma_f32_16x16x32_bf16(a, bh[nt],  acc[tt][nt], 0, 0, 0);
                        acc[tt][nt] = __builtin_amdgcn_mfma_f32_16x16x32_bf16(a, blo[nt], acc[tt][nt], 0, 0, 0);
                    }
                }
            }
        }

        // ---- sequential mem1 update (registers only, order unchanged) ----
#pragma unroll
        for (int tt = 0; tt < 2; ++tt)
#pragma unroll
            for (int nt = 0; nt < 2; ++nt)
#pragma unroll
                for (int r = 0; r < 4; ++r) {
                    float m = 0.95f * mem1[nt][r] + acc[tt][nt][r];
                    m = m + b1v[nt];
                    float o = (m > 1.0f) ? 1.0f : 0.0f;
                    mem1[nt][r] = m - o;
                    cnt[nt][r] += o;
                }
    }

    // ---- epilogue: counts -> LDS -> layer-2 matmul ----
#pragma unroll
    for (int nt = 0; nt < 2; ++nt)
#pragma unroll
        for (int r = 0; r < 4; ++r)
            s_cnt[l4 * 4 + r][n_off + nt * 16 + l15] = cnt[nt][r];
    __syncthreads();
    for (int idx = tid; idx < WG_ROWS * C_DIM; idx += 256) {
        int bl_ = idx / C_DIM, c_ = idx - bl_ * C_DIM;
        float s_ = 0.0f;
        for (int h_ = 0; h_ < H_DIM; ++h_) s_ += s_cnt[bl_][h_] * W2[c_ * H_DIM + h_];
        out[(size_t)(row0 + bl_) * C_DIM + c_] = s_ * 0.125f + b2[c_];
    }
}

extern "C" void kernel_launch(void* const* d_in, const int* in_sizes, int n_in,
                              void* d_out, int out_size, void* d_ws, size_t ws_size,
                              hipStream_t stream) {
    const float* inp = (const float*)d_in[0];
    const float* rnd = (const float*)d_in[1];
    const float* W1  = (const float*)d_in[2];
    const float* b1  = (const float*)d_in[3];
    const float* W2  = (const float*)d_in[4];
    const float* b2  = (const float*)d_in[5];
    float* out = (float*)d_out;

    unsigned short* w1hi = (unsigned short*)d_ws;
    unsigned short* w1lo = w1hi + HP * KP;
    float* b1p = (float*)(w1lo + HP * KP);

    prep_kernel<<<(HP * KP + 255) / 256, 256, 0, stream>>>(W1, b1, w1hi, w1lo, b1p);
    snn_main<<<B_TOT / WG_ROWS, 256, 0, stream>>>(inp, rnd, w1hi, w1lo, b1p, W2, b2, out);
}